// Round 4
// baseline (201.533 us; speedup 1.0000x reference)
//
#include <hip/hip_runtime.h>

// ---------------------------------------------------------------------------
// RoPE Multi-Headed Attention (quirky softmax(exp(qr·kr)/den) variant)
// B=2, S=2048, D=1024, H=16, HD=64
// ---------------------------------------------------------------------------

#define Bn 2
#define Sn 2048
#define Dn 1024
#define Hn 16
#define HDn 64

typedef __attribute__((ext_vector_type(8))) short bf16x8;
typedef __attribute__((ext_vector_type(8))) unsigned short u16x8;
typedef __attribute__((ext_vector_type(4))) unsigned short u16x4;
typedef __attribute__((ext_vector_type(4))) float f32x4;

#define MFMA(a, b, c) __builtin_amdgcn_mfma_f32_16x16x32_bf16(a, b, c, 0, 0, 0)
#define Z4 ((f32x4){0.f, 0.f, 0.f, 0.f})

// 0.125 * log2(e): folds both the 1/sqrt(HD) scale and the exp->exp2 change
#define PRESC 0.18033688011112042f
// log2(log2(e)): A = a*log2(e) = 2^(s' - L2 + C2)
#define C2 0.5287663729448977f

__device__ __forceinline__ unsigned short f2bf(float f) {
  unsigned int u = __builtin_bit_cast(unsigned int, f);
  u = (u + 0x7fffu + ((u >> 16) & 1u)) >> 16;
  return (unsigned short)u;
}

__device__ __forceinline__ unsigned int cvtpk(float lo, float hi) {
  unsigned int r;
  asm("v_cvt_pk_bf16_f32 %0, %1, %2" : "=v"(r) : "v"(lo), "v"(hi));
  return r;
}

// async global->LDS, 16B per lane; dst is wave-uniform base (lane writes +lane*16B)
__device__ __forceinline__ void gll16(const unsigned short* g, unsigned short* l) {
  __builtin_amdgcn_global_load_lds((const __attribute__((address_space(1))) void*)g,
                                   (__attribute__((address_space(3))) void*)l, 16, 0, 0);
}

// swizzled fragment read: LDS slot c of row r holds source chunk c^(r&7)
#define FR(T, row, x) (*(const bf16x8*)&(T)[(row) * 64 + (((x) ^ ((row) & 7)) * 8)])

// ---------------------------------------------------------------------------
// 0. cos/sin table: T[s*32+i] = (cos(s*theta_i), sin(s*theta_i))
// ---------------------------------------------------------------------------
__global__ __launch_bounds__(256) void k_trig(float2* __restrict__ T) {
  int idx = blockIdx.x * 256 + threadIdx.x;  // 65536
  int s = idx >> 5, i = idx & 31;
  float theta = powf(1000.f, -(float)i / 32.f);
  float pm = (float)s * theta;
  T[idx] = make_float2(cosf(pm), sinf(pm));
}

// ---------------------------------------------------------------------------
// 1. Weight transpose+convert: W[k][n] f32 -> Wt[n][k] bf16   (4 weights)
// ---------------------------------------------------------------------------
__global__ __launch_bounds__(256) void k_wtrans(
    const float* __restrict__ W0, const float* __restrict__ W1,
    const float* __restrict__ W2, const float* __restrict__ W3,
    unsigned short* __restrict__ O0, unsigned short* __restrict__ O1,
    unsigned short* __restrict__ O2, unsigned short* __restrict__ O3) {
  __shared__ float t[64][65];
  int which = blockIdx.z;
  const float* W = (which == 0) ? W0 : (which == 1) ? W1 : (which == 2) ? W2 : W3;
  unsigned short* O = (which == 0) ? O0 : (which == 1) ? O1 : (which == 2) ? O2 : O3;
  int kb = blockIdx.x * 64, nb = blockIdx.y * 64;
  int tid = threadIdx.x;
#pragma unroll
  for (int rep = 0; rep < 16; ++rep) {
    int e = rep * 256 + tid;
    int k = e >> 6, n = e & 63;
    t[k][n] = W[(kb + k) * Dn + nb + n];
  }
  __syncthreads();
#pragma unroll
  for (int rep = 0; rep < 16; ++rep) {
    int e = rep * 256 + tid;
    int n = e >> 6, k = e & 63;
    O[(nb + n) * Dn + kb + k] = f2bf(t[k][n]);
  }
}

// ---------------------------------------------------------------------------
// 2. Activation convert f32 -> bf16. grid (2048, 3); y picks tensor.
// ---------------------------------------------------------------------------
__global__ __launch_bounds__(256) void k_cvt(
    const float* __restrict__ q, const float* __restrict__ k, const float* __restrict__ v,
    unsigned short* __restrict__ oq, unsigned short* __restrict__ ok,
    unsigned short* __restrict__ ov) {
  int z = blockIdx.y;
  const float* s = (z == 0) ? q : (z == 1) ? k : v;
  unsigned short* d = (z == 0) ? oq : (z == 1) ? ok : ov;
  size_t idx = ((size_t)blockIdx.x * 256 + threadIdx.x) * 8;
  float4 a = *(const float4*)(s + idx);
  float4 b = *(const float4*)(s + idx + 4);
  u16x8 pk;
  pk[0] = f2bf(a.x); pk[1] = f2bf(a.y); pk[2] = f2bf(a.z); pk[3] = f2bf(a.w);
  pk[4] = f2bf(b.x); pk[5] = f2bf(b.y); pk[6] = f2bf(b.z); pk[7] = f2bf(b.w);
  *(u16x8*)(d + idx) = pk;
}

// ---------------------------------------------------------------------------
// 3. Fused QKV projection GEMM (gll-staged). grid (32, 8, 3); z = {Q,K,V}.
//    Q: prescaled by PRESC; Q/K write base + roped; V writes Vt [b,h,hd,s].
// ---------------------------------------------------------------------------
__global__ __launch_bounds__(256) void k_gemm_proj(
    const unsigned short* __restrict__ Qa, const unsigned short* __restrict__ Ka,
    const unsigned short* __restrict__ Va,
    const unsigned short* __restrict__ Wq, const unsigned short* __restrict__ Wk,
    const unsigned short* __restrict__ Wv,
    const float* __restrict__ bqp, const float* __restrict__ bkp, const float* __restrict__ bvp,
    const float2* __restrict__ trig,
    unsigned short* __restrict__ Qb, unsigned short* __restrict__ Kb,
    unsigned short* __restrict__ Qr, unsigned short* __restrict__ Kr,
    unsigned short* __restrict__ Vt) {
  __shared__ unsigned short Al[128 * 64];
  __shared__ unsigned short Bl[128 * 64];
  const int tid = threadIdx.x;
  const int wave = tid >> 6, lane = tid & 63, g = lane >> 4, li = lane & 15;
  const int mbase = blockIdx.x * 128, nbase = blockIdx.y * 128;
  const int wm = wave >> 1, wn = wave & 1;
  const int which = blockIdx.z;
  const unsigned short* A = (which == 0) ? Qa : (which == 1) ? Ka : Va;
  const unsigned short* Wt = (which == 0) ? Wq : (which == 1) ? Wk : Wv;
  const float* bias = (which == 0) ? bqp : (which == 1) ? bkp : bvp;

  f32x4 acc[4][4];
#pragma unroll
  for (int i = 0; i < 4; ++i)
#pragma unroll
    for (int j = 0; j < 4; ++j) acc[i][j] = Z4;

  float bv4[4];
#pragma unroll
  for (int nt = 0; nt < 4; ++nt) bv4[nt] = bias[nbase + wn * 64 + nt * 16 + li];

  const int lr8 = lane >> 3, lc = lane & 7;
  const int xc8 = (lc ^ lr8) * 8;
  const unsigned short* srcA = A + (size_t)(mbase + wave * 32 + lr8) * Dn + xc8;
  const unsigned short* srcB = Wt + (size_t)(nbase + wave * 32 + lr8) * Dn + xc8;

  for (int kb = 0; kb < Dn; kb += 64) {
    __syncthreads();
#pragma unroll
    for (int i = 0; i < 4; ++i) {
      gll16(srcA + kb + (size_t)i * (8 * Dn), &Al[(wave * 32 + i * 8) * 64]);
      gll16(srcB + kb + (size_t)i * (8 * Dn), &Bl[(wave * 32 + i * 8) * 64]);
    }
    __syncthreads();
#pragma unroll
    for (int kc = 0; kc < 2; ++kc) {
      bf16x8 af[4], bfr[4];
#pragma unroll
      for (int mt = 0; mt < 4; ++mt) af[mt] = FR(Al, wm * 64 + mt * 16 + li, kc * 4 + g);
#pragma unroll
      for (int nt = 0; nt < 4; ++nt) bfr[nt] = FR(Bl, wn * 64 + nt * 16 + li, kc * 4 + g);
#pragma unroll
      for (int mt = 0; mt < 4; ++mt)
#pragma unroll
        for (int nt = 0; nt < 4; ++nt)
          acc[mt][nt] = MFMA(af[mt], bfr[nt], acc[mt][nt]);
    }
  }

  if (which < 2) {
    unsigned short* Ob = (which == 0) ? Qb : Kb;
    unsigned short* Or = (which == 0) ? Qr : Kr;
    const float presc = (which == 0) ? PRESC : 1.f;
#pragma unroll
    for (int mt = 0; mt < 4; ++mt) {
#pragma unroll
      for (int nt = 0; nt < 4; ++nt) {
        const int n = nbase + wn * 64 + nt * 16 + li;
        const int h = n >> 6, hd = n & 63;
        const int ti = hd >> 1;
        const float sgn = (hd & 1) ? 1.f : -1.f;
#pragma unroll
        for (int r = 0; r < 4; ++r) {
          const int m = mbase + wm * 64 + mt * 16 + 4 * g + r;
          const int b = m >> 11, s = m & (Sn - 1);
          const float v = (acc[mt][nt][r] + bv4[nt]) * presc;
          const size_t oi = (((size_t)(b * Hn + h)) * Sn + s) * HDn + hd;
          Ob[oi] = f2bf(v);
          const float p = __shfl_xor(v, 1);
          const float2 cs = trig[(s << 5) + ti];
          Or[oi] = f2bf(fmaf(sgn * p, cs.y, v * cs.x));
        }
      }
    }
  } else {
#pragma unroll
    for (int mt = 0; mt < 4; ++mt) {
#pragma unroll
      for (int nt = 0; nt < 4; ++nt) {
        const int n = nbase + wn * 64 + nt * 16 + li;
        const int h = n >> 6, hd = n & 63;
        const int m0 = mbase + wm * 64 + mt * 16 + 4 * g;
        const int b = m0 >> 11, s0 = m0 & (Sn - 1);
        u16x4 pk;
#pragma unroll
        for (int r = 0; r < 4; ++r) pk[r] = f2bf(acc[mt][nt][r] + bv4[nt]);
        *(u16x4*)&Vt[(((size_t)(b * Hn + h)) * HDn + hd) * Sn + s0] = pk;
      }
    }
  }
}

// ---------------------------------------------------------------------------
// 4. Output GEMM 64x128 tile (gll-staged): A bf16 [4096][1024], out f32 + bias
// ---------------------------------------------------------------------------
__global__ __launch_bounds__(256) void k_gemm_out(const unsigned short* __restrict__ A,
                                                  const unsigned short* __restrict__ Wt,
                                                  const float* __restrict__ bias,
                                                  float* __restrict__ out) {
  __shared__ unsigned short Al[64 * 64];
  __shared__ unsigned short Bl[128 * 64];
  const int tid = threadIdx.x;
  const int wave = tid >> 6, lane = tid & 63, g = lane >> 4, li = lane & 15;
  const int mbase = blockIdx.x * 64, nbase = blockIdx.y * 128;
  const int wm = wave >> 1, wn = wave & 1;

  f32x4 acc[2][4];
#pragma unroll
  for (int i = 0; i < 2; ++i)
#pragma unroll
    for (int j = 0; j < 4; ++j) acc[i][j] = Z4;

  float bv4[4];
#pragma unroll
  for (int nt = 0; nt < 4; ++nt) bv4[nt] = bias[nbase + wn * 64 + nt * 16 + li];

  const int lr8 = lane >> 3, lc = lane & 7;
  const int xc8 = (lc ^ lr8) * 8;
  const unsigned short* srcA = A + (size_t)(mbase + wave * 16 + lr8) * Dn + xc8;
  const unsigned short* srcB = Wt + (size_t)(nbase + wave * 32 + lr8) * Dn + xc8;

  for (int kb = 0; kb < Dn; kb += 64) {
    __syncthreads();
#pragma unroll
    for (int i = 0; i < 2; ++i)
      gll16(srcA + kb + (size_t)i * (8 * Dn), &Al[(wave * 16 + i * 8) * 64]);
#pragma unroll
    for (int i = 0; i < 4; ++i)
      gll16(srcB + kb + (size_t)i * (8 * Dn), &Bl[(wave * 32 + i * 8) * 64]);
    __syncthreads();
#pragma unroll
    for (int kc = 0; kc < 2; ++kc) {
      bf16x8 af[2], bfr[4];
#pragma unroll
      for (int mt = 0; mt < 2; ++mt) af[mt] = FR(Al, wm * 32 + mt * 16 + li, kc * 4 + g);
#pragma unroll
      for (int nt = 0; nt < 4; ++nt) bfr[nt] = FR(Bl, wn * 64 + nt * 16 + li, kc * 4 + g);
#pragma unroll
      for (int mt = 0; mt < 2; ++mt)
#pragma unroll
        for (int nt = 0; nt < 4; ++nt)
          acc[mt][nt] = MFMA(af[mt], bfr[nt], acc[mt][nt]);
    }
  }

#pragma unroll
  for (int mt = 0; mt < 2; ++mt)
#pragma unroll
    for (int nt = 0; nt < 4; ++nt) {
      const int n = nbase + wn * 64 + nt * 16 + li;
#pragma unroll
      for (int r = 0; r < 4; ++r) {
        const int m = mbase + wm * 32 + mt * 16 + 4 * g + r;
        out[(size_t)m * Dn + n] = acc[mt][nt][r] + bv4[nt];
      }
    }
}

// ---------------------------------------------------------------------------
// 5. Attention, swapped-QK^T + exp2 algebra + online max.
//    grid (bh=32, f=16). Block handles q-tiles f and 31-f.
//    Pass A: den only (Kb staged, 128-row tiles). Lane owns q=li per 16-block.
//    Pass B: A=2^(s'-Lc) online-max, w=2^(A-m), packed b64 P-stores, PV.
// ---------------------------------------------------------------------------
__global__ __launch_bounds__(256) void k_attn(
    const unsigned short* __restrict__ Qr, const unsigned short* __restrict__ Kr,
    const unsigned short* __restrict__ Qb, const unsigned short* __restrict__ Kb,
    const unsigned short* __restrict__ Vt, unsigned short* __restrict__ Zb) {
  __shared__ unsigned short KT[2][2][64 * 64];  // 32KB: passA = [buf] 128x64 Kb; passB = [buf][Kr|Vt]
  __shared__ unsigned short Pl[4][2][16 * 64];  // 16KB per-wave P

  const int tid = threadIdx.x;
  const int wave = tid >> 6, lane = tid & 63, g = lane >> 4, li = lane & 15;
  const int bh = blockIdx.x, f = blockIdx.y;
  const int qtL = f, qtH = 31 - f;
  const int qwL = qtL * 64 + wave * 16, qwH = qtH * 64 + wave * 16;
  const size_t kvbase = (size_t)bh * (Sn * HDn);

  // Q fragments (prescaled by PRESC at projection)
  bf16x8 qrfL[2], qbfL[2], qrfH[2], qbfH[2];
#pragma unroll
  for (int kc = 0; kc < 2; ++kc) {
    const size_t aL = kvbase + (size_t)(qwL + li) * HDn + kc * 32 + g * 8;
    const size_t aH = kvbase + (size_t)(qwH + li) * HDn + kc * 32 + g * 8;
    qrfL[kc] = *(const bf16x8*)(Qr + aL);
    qbfL[kc] = *(const bf16x8*)(Qb + aL);
    qrfH[kc] = *(const bf16x8*)(Qr + aH);
    qbfH[kc] = *(const bf16x8*)(Qb + aH);
  }

  const int lr8 = lane >> 3, lc = lane & 7;
  const int xc8 = (lc ^ lr8) * 8;  // source-side swizzle
  unsigned short* KTf = &KT[0][0][0];
  unsigned short* myPL = &Pl[wave][0][0];
  unsigned short* myPH = &Pl[wave][1][0];

  // pass A staging: whole block stages one 128x64 Kb tile; wave covers 32 rows
  const unsigned short* srcPA = Kb + kvbase + (size_t)(wave * 32 + lr8) * HDn + xc8;
  // pass B staging: tw = tensor (0=Kr,1=Vt), rb = row base
  const int tw = wave >> 1;
  const int rb = (wave & 1) * 32;
  const unsigned short* srcKrB = Kr + kvbase + (size_t)(rb + lr8) * HDn + xc8;
  const unsigned short* srcVtB = Vt + kvbase + (size_t)(rb + lr8) * Sn + xc8;
  const size_t strI = tw ? (size_t)(8 * Sn) : (size_t)(8 * HDn);

#define STAGE_PA(kb_, buf_)                                          \
  do {                                                               \
    unsigned short* d_ = KTf + (buf_)*8192 + (wave * 32) * 64;       \
    const unsigned short* s_ = srcPA + (size_t)(kb_)*HDn;            \
    gll16(s_, d_);                                                   \
    gll16(s_ + 8 * HDn, d_ + 8 * 64);                                \
    gll16(s_ + 16 * HDn, d_ + 16 * 64);                              \
    gll16(s_ + 24 * HDn, d_ + 24 * 64);                              \
  } while (0)

#define STAGE_B(kb_, buf_)                                                         \
  do {                                                                             \
    unsigned short* d_ = KTf + (buf_)*8192 + tw * 4096 + rb * 64;                  \
    const unsigned short* s_ =                                                     \
        tw ? (srcVtB + (size_t)(kb_)) : (srcKrB + (size_t)(kb_)*HDn);              \
    gll16(s_, d_);                                                                 \
    gll16(s_ + strI, d_ + 8 * 64);                                                 \
    gll16(s_ + 2 * strI, d_ + 16 * 64);                                            \
    gll16(s_ + 3 * strI, d_ + 24 * 64);                                            \
  } while (0)

  // ------------------- PASS A: den = sum_k 2^(s') over ALL k -------------------
  float dL = 0.f, dH = 0.f;
  STAGE_PA(0, 0);
  __syncthreads();
  int cur = 0;
  for (int t = 0; t < Sn / 128; ++t) {
    if (t + 1 < Sn / 128) STAGE_PA((t + 1) * 128, cur ^ 1);
    const unsigned short* TK = KTf + cur * 8192;
#pragma unroll
    for (int nt = 0; nt < 8; ++nt) {
      const int krow = nt * 16 + li;
      const bf16x8 kf0 = FR(TK, krow, g), kf1 = FR(TK, krow, 4 + g);
      f32x4 sL = Z4, sH = Z4;
      sL = MFMA(kf0, qbfL[0], sL);
      sL = MFMA(kf1, qbfL[1], sL);
      sH = MFMA(kf0, qbfH[0], sH);
      sH = MFMA(kf1, qbfH[1], sH);
#pragma unroll
      for (int r = 0; r < 4; ++r) {
        dL += exp2f(sL[r]);
        dH += exp2f(sH[r]);
      }
    }
    __syncthreads();
    cur ^= 1;
  }
  dL += __shfl_xor(dL, 16);
  dL += __shfl_xor(dL, 32);
  dH += __shfl_xor(dH, 16);
  dH += __shfl_xor(dH, 32);
  const float LcL = __log2f(dL) - C2;  // A = 2^(s' - Lc) = a*log2(e)
  const float LcH = __log2f(dH) - C2;

  // ------------------- PASS B -------------------
  f32x4 acczL[4], acczH[4];
#pragma unroll
  for (int i = 0; i < 4; ++i) {
    acczL[i] = Z4;
    acczH[i] = Z4;
  }
  float wsumL = 0.f, wsumH = 0.f, mL = 0.f, mH = 0.f;
  const int NTB = qtH + 1;

  STAGE_B(0, 0);
  __syncthreads();
  cur = 0;
  for (int t = 0; t < NTB; ++t) {
    if (t + 1 < NTB) STAGE_B((t + 1) * 64, cur ^ 1);
    const unsigned short* T0 = KTf + cur * 8192;         // Kr
    const unsigned short* TV = KTf + cur * 8192 + 4096;  // Vt [hd][k]
    const int kb = t * 64;
    const bool loAct = (t <= qtL);
    float AvH[4][4], AvL[4][4];

#pragma unroll
    for (int nt = 0; nt < 4; ++nt) {
      const int ktile = kb + nt * 16;
      const int krow = nt * 16 + li;
      const bf16x8 kf0 = FR(T0, krow, g), kf1 = FR(T0, krow, 4 + g);
      // H half: lane owns q = qwH + li; regs own k = ktile + 4g + r
      if (ktile <= qwH + 15) {
        f32x4 s = Z4;
        s = MFMA(kf0, qrfH[0], s);
        s = MFMA(kf1, qrfH[1], s);
        const bool diag = (ktile + 15 > qwH);
#pragma unroll
        for (int r = 0; r < 4; ++r) {
          float a = exp2f(s[r] - LcH);
          if (diag && (ktile + 4 * g + r > qwH + li)) a = -1.f;
          AvH[nt][r] = a;
        }
      } else {
#pragma unroll
        for (int r = 0; r < 4; ++r) AvH[nt][r] = -1.f;
      }
      // L half
      if (loAct) {
        if (ktile <= qwL + 15) {
          f32x4 s = Z4;
          s = MFMA(kf0, qrfL[0], s);
          s = MFMA(kf1, qrfL[1], s);
          const bool diag = (ktile + 15 > qwL);
#pragma unroll
          for (int r = 0; r < 4; ++r) {
            float a = exp2f(s[r] - LcL);
            if (diag && (ktile + 4 * g + r > qwL + li)) a = -1.f;
            AvL[nt][r] = a;
          }
        } else {
#pragma unroll
          for (int r = 0; r < 4; ++r) AvL[nt][r] = -1.f;
        }
      }
    }

    // ---- H finish: online max, w = 2^(A-m), pack, PV ----
    {
      float tm = AvH[0][0];
#pragma unroll
      for (int nt = 0; nt < 4; ++nt)
#pragma unroll
        for (int r = 0; r < 4; ++r) tm = fmaxf(tm, AvH[nt][r]);
      tm = fmaxf(tm, __shfl_xor(tm, 16));
      tm = fmaxf(tm, __shfl_xor(tm, 32));
      if (!__all(tm <= mH + 8.f)) {  // rare rescale (defer threshold)
        const float mn = fmaxf(mH, tm);
        const float sc = exp2f(mH - mn);
        mH = mn;
        wsumH *= sc;
#pragma unroll
        for (int r = 0; r < 4; ++r) {
          const float scr = __shfl(sc, 4 * g + r);
#pragma unroll
          for (int n2 = 0; n2 < 4; ++n2) acczH[n2][r] *= scr;
        }
      }
#pragma unroll
      for (int nt = 0; nt < 4; ++nt) {
        float w[4];
#pragma unroll
        for (int r = 0; r < 4; ++r) {
          const float e = exp2f(AvH[nt][r] - mH);
          w[r] = (AvH[nt][r] >= 0.f) ? e : 0.f;
          wsumH += w[r];
        }
        const int adr = li * 64 + (((nt * 2 + (g >> 1)) ^ (li & 7)) * 8) + (g & 1) * 4;
        *(uint2*)&myPH[adr] = (uint2){cvtpk(w[0], w[1]), cvtpk(w[2], w[3])};
      }
#pragma unroll
      for (int kc = 0; kc < 2; ++kc) {
        const bf16x8 pa = FR(myPH, li, kc * 4 + g);
#pragma unroll
        for (int n2 = 0; n2 < 4; ++n2) {
          const bf16x8 vb = FR(TV, n2 * 16 + li, kc * 4 + g);
          acczH[n2] = MFMA(pa, vb, acczH[n2]);
        }
      }
    }
    // ---- L finish ----
    if (loAct) {
      float tm = AvL[0][0];
#pragma unroll
      for (int nt = 0; nt < 4; ++nt)
#pragma unroll
        for (int r = 0; r < 4; ++r) tm = fmaxf(tm, AvL[nt][r]);
      tm = fmaxf(tm, __shfl_xor(tm, 16));
      tm = fmaxf(tm, __shfl_xor(tm, 32));
      if (!__all(tm <= mL + 8.f)) {
        const float mn = fmaxf(mL, tm);
        const float sc = exp2f(mL - mn);
        mL = mn;
        wsumL *= sc;
#pragma unroll
        for (int r = 0; r < 4; ++r) {
          const float scr = __shfl(sc, 4 * g + r);
#pragma unroll
          for (int n2 = 0; n2 < 4; ++n2) acczL[n2][r] *= scr;
        }
      }
#pragma unroll
      for (int nt = 0; nt < 4; ++nt) {
        float w[4];
#pragma unroll
        for (int r = 0; r < 4; ++r) {
          const float e = exp2f(AvL[nt][r] - mL);
          w[r] = (AvL[nt][r] >= 0.f) ? e : 0.f;
          wsumL += w[r];
        }
        const int adr = li * 64 + (((nt * 2 + (g >> 1)) ^ (li & 7)) * 8) + (g & 1) * 4;
        *(uint2*)&myPL[adr] = (uint2){cvtpk(w[0], w[1]), cvtpk(w[2], w[3])};
      }
#pragma unroll
      for (int kc = 0; kc < 2; ++kc) {
        const bf16x8 pa = FR(myPL, li, kc * 4 + g);
#pragma unroll
        for (int n2 = 0; n2 < 4; ++n2) {
          const bf16x8 vb = FR(TV, n2 * 16 + li, kc * 4 + g);
          acczL[n2] = MFMA(pa, vb, acczL[n2]);
        }
      }
    }
    __syncthreads();
    cur ^= 1;
  }

  // normalize + write bf16 [b*S+q][H*HD]
  wsumL += __shfl_xor(wsumL, 16);
  wsumL += __shfl_xor(wsumL, 32);
  wsumH += __shfl_xor(wsumH, 16);
  wsumH += __shfl_xor(wsumH, 32);
  const int b = bh >> 4, h = bh & 15;
#pragma unroll
  for (int n2 = 0; n2 < 4; ++n2) {
#pragma unroll
    for (int r = 0; r < 4; ++r) {
      const int hd = n2 * 16 + li;
      const int qL = qwL + 4 * g + r;
      const int qH = qwH + 4 * g + r;
      const float wqL = __shfl(wsumL, 4 * g + r);
      const float wqH = __shfl(wsumH, 4 * g + r);
      Zb[((size_t)(b * Sn + qL)) * Dn + h * HDn + hd] = f2bf(acczL[n2][r] / wqL);
      Zb[((size_t)(b * Sn + qH)) * Dn + h * HDn + hd] = f2bf(acczH[n2][r] / wqH);
    }
  }
#undef STAGE_PA
#undef STAGE_B
}

// ---------------------------------------------------------------------------
extern "C" void kernel_launch(void* const* d_in, const int* in_sizes, int n_in,
                              void* d_out, int out_size, void* d_ws, size_t ws_size,
                              hipStream_t stream) {
  const float* query = (const float*)d_in[0];
  const float* key   = (const float*)d_in[1];
  const float* value = (const float*)d_in[2];
  const float* Wq = (const float*)d_in[4];
  const float* bq = (const float*)d_in[5];
  const float* Wk = (const float*)d_in[6];
  const float* bk = (const float*)d_in[7];
  const float* Wv = (const float*)d_in[8];
  const float* bv = (const float*)d_in[9];
  const float* Wo = (const float*)d_in[10];
  const float* bo = (const float*)d_in[11];

  char* ws = (char*)d_ws;
  const size_t MB = 1ull << 20;
  unsigned short* Wqt = (unsigned short*)(ws + 0 * MB);
  unsigned short* Wkt = (unsigned short*)(ws + 2 * MB);
  unsigned short* Wvt = (unsigned short*)(ws + 4 * MB);
  unsigned short* Wot = (unsigned short*)(ws + 6 * MB);
  float2* trig        = (float2*)(ws + 8 * MB);           // 512 KB
  unsigned short* Qa  = (unsigned short*)(ws + 9 * MB);   // bf16 activations
  unsigned short* Ka  = (unsigned short*)(ws + 17 * MB);
  unsigned short* Va  = (unsigned short*)(ws + 25 * MB);
  unsigned short* Qb  = (unsigned short*)(ws + 33 * MB);  // [b,h,s,hd] bf16 (Q prescaled)
  unsigned short* Kb  = (unsigned short*)(ws + 41 * MB);
  unsigned short* Qr  = (unsigned short*)(ws + 49 * MB);
  unsigned short* Kr  = (unsigned short*)(ws + 57 * MB);
  unsigned short* Vt  = (unsigned short*)(ws + 65 * MB);  // [b,h,hd,s] bf16
  unsigned short* Zb  = (unsigned short*)(ws + 73 * MB);  // [m][1024] bf16

  k_trig<<<256, 256, 0, stream>>>(trig);
  k_wtrans<<<dim3(16, 16, 4), 256, 0, stream>>>(Wq, Wk, Wv, Wo, Wqt, Wkt, Wvt, Wot);
  k_cvt<<<dim3(2048, 3), 256, 0, stream>>>(query, key, value, Qa, Ka, Va);
  k_gemm_proj<<<dim3(32, 8, 3), 256, 0, stream>>>(Qa, Ka, Va, Wqt, Wkt, Wvt,
                                                  bq, bk, bv, trig, Qb, Kb, Qr, Kr, Vt);
  k_attn<<<dim3(32, 16), 256, 0, stream>>>(Qr, Kr, Qb, Kb, Vt, Zb);
  k_gemm_out<<<dim3(64, 8), 256, 0, stream>>>(Zb, Wot, bo, (float*)d_out);
}

// Round 5
// 157.827 us; speedup vs baseline: 1.2769x; 1.2769x over previous
//
#include <hip/hip_runtime.h>

// ---------------------------------------------------------------------------
// RoPE Multi-Headed Attention (quirky softmax(exp(qr·kr)/den) variant)
// B=2, S=2048, D=1024, H=16, HD=64
// ---------------------------------------------------------------------------

#define Bn 2
#define Sn 2048
#define Dn 1024
#define Hn 16
#define HDn 64

typedef __attribute__((ext_vector_type(8))) short bf16x8;
typedef __attribute__((ext_vector_type(8))) unsigned short u16x8;
typedef __attribute__((ext_vector_type(4))) unsigned short u16x4;
typedef __attribute__((ext_vector_type(4))) float f32x4;

#define MFMA(a, b, c) __builtin_amdgcn_mfma_f32_16x16x32_bf16(a, b, c, 0, 0, 0)
#define Z4 ((f32x4){0.f, 0.f, 0.f, 0.f})

// 0.125 * log2(e): folds both the 1/sqrt(HD) scale and the exp->exp2 change
#define PRESC 0.18033688011112042f
// log2(log2(e)): A = a*log2(e) = 2^(s' - L2 + C2)
#define C2 0.5287663729448977f

#define EXP2(x) __builtin_amdgcn_exp2f(x)
#define LOG2(x) __builtin_amdgcn_logf(x)

__device__ __forceinline__ unsigned short f2bf(float f) {
  unsigned int u = __builtin_bit_cast(unsigned int, f);
  u = (u + 0x7fffu + ((u >> 16) & 1u)) >> 16;
  return (unsigned short)u;
}

__device__ __forceinline__ unsigned int cvtpk(float lo, float hi) {
  unsigned int r;
  asm("v_cvt_pk_bf16_f32 %0, %1, %2" : "=v"(r) : "v"(lo), "v"(hi));
  return r;
}

// async global->LDS, 16B per lane; dst is wave-uniform base (lane writes +lane*16B)
__device__ __forceinline__ void gll16(const unsigned short* g, unsigned short* l) {
  __builtin_amdgcn_global_load_lds((const __attribute__((address_space(1))) void*)g,
                                   (__attribute__((address_space(3))) void*)l, 16, 0, 0);
}

// swizzled fragment read: LDS slot c of row r holds source chunk c^(r&7)
#define FR(T, row, x) (*(const bf16x8*)&(T)[(row) * 64 + (((x) ^ ((row) & 7)) * 8)])

// ---------------------------------------------------------------------------
// 0. cos/sin table: T[s*32+i] = (cos(s*theta_i), sin(s*theta_i))
// ---------------------------------------------------------------------------
__global__ __launch_bounds__(256) void k_trig(float2* __restrict__ T) {
  int idx = blockIdx.x * 256 + threadIdx.x;  // 65536
  int s = idx >> 5, i = idx & 31;
  float theta = powf(1000.f, -(float)i / 32.f);
  float pm = (float)s * theta;
  T[idx] = make_float2(cosf(pm), sinf(pm));
}

// ---------------------------------------------------------------------------
// 1. Weight transpose+convert: W[k][n] f32 -> Wt[n][k] bf16   (4 weights)
// ---------------------------------------------------------------------------
__global__ __launch_bounds__(256) void k_wtrans(
    const float* __restrict__ W0, const float* __restrict__ W1,
    const float* __restrict__ W2, const float* __restrict__ W3,
    unsigned short* __restrict__ O0, unsigned short* __restrict__ O1,
    unsigned short* __restrict__ O2, unsigned short* __restrict__ O3) {
  __shared__ float t[64][65];
  int which = blockIdx.z;
  const float* W = (which == 0) ? W0 : (which == 1) ? W1 : (which == 2) ? W2 : W3;
  unsigned short* O = (which == 0) ? O0 : (which == 1) ? O1 : (which == 2) ? O2 : O3;
  int kb = blockIdx.x * 64, nb = blockIdx.y * 64;
  int tid = threadIdx.x;
#pragma unroll
  for (int rep = 0; rep < 16; ++rep) {
    int e = rep * 256 + tid;
    int k = e >> 6, n = e & 63;
    t[k][n] = W[(kb + k) * Dn + nb + n];
  }
  __syncthreads();
#pragma unroll
  for (int rep = 0; rep < 16; ++rep) {
    int e = rep * 256 + tid;
    int n = e >> 6, k = e & 63;
    O[(nb + n) * Dn + kb + k] = f2bf(t[k][n]);
  }
}

// ---------------------------------------------------------------------------
// 2. Activation convert f32 -> bf16. grid (2048, 3); y picks tensor.
// ---------------------------------------------------------------------------
__global__ __launch_bounds__(256) void k_cvt(
    const float* __restrict__ q, const float* __restrict__ k, const float* __restrict__ v,
    unsigned short* __restrict__ oq, unsigned short* __restrict__ ok,
    unsigned short* __restrict__ ov) {
  int z = blockIdx.y;
  const float* s = (z == 0) ? q : (z == 1) ? k : v;
  unsigned short* d = (z == 0) ? oq : (z == 1) ? ok : ov;
  size_t idx = ((size_t)blockIdx.x * 256 + threadIdx.x) * 8;
  float4 a = *(const float4*)(s + idx);
  float4 b = *(const float4*)(s + idx + 4);
  u16x8 pk;
  pk[0] = f2bf(a.x); pk[1] = f2bf(a.y); pk[2] = f2bf(a.z); pk[3] = f2bf(a.w);
  pk[4] = f2bf(b.x); pk[5] = f2bf(b.y); pk[6] = f2bf(b.z); pk[7] = f2bf(b.w);
  *(u16x8*)(d + idx) = pk;
}

// ---------------------------------------------------------------------------
// 3. Fused QKV projection GEMM (gll-staged). grid (32, 8, 3); z = {Q,K,V}.
//    Q: prescaled by PRESC; Q/K write base + roped; V writes Vt [b,h,hd,s].
// ---------------------------------------------------------------------------
__global__ __launch_bounds__(256) void k_gemm_proj(
    const unsigned short* __restrict__ Qa, const unsigned short* __restrict__ Ka,
    const unsigned short* __restrict__ Va,
    const unsigned short* __restrict__ Wq, const unsigned short* __restrict__ Wk,
    const unsigned short* __restrict__ Wv,
    const float* __restrict__ bqp, const float* __restrict__ bkp, const float* __restrict__ bvp,
    const float2* __restrict__ trig,
    unsigned short* __restrict__ Qb, unsigned short* __restrict__ Kb,
    unsigned short* __restrict__ Qr, unsigned short* __restrict__ Kr,
    unsigned short* __restrict__ Vt) {
  __shared__ unsigned short Al[128 * 64];
  __shared__ unsigned short Bl[128 * 64];
  const int tid = threadIdx.x;
  const int wave = tid >> 6, lane = tid & 63, g = lane >> 4, li = lane & 15;
  const int mbase = blockIdx.x * 128, nbase = blockIdx.y * 128;
  const int wm = wave >> 1, wn = wave & 1;
  const int which = blockIdx.z;
  const unsigned short* A = (which == 0) ? Qa : (which == 1) ? Ka : Va;
  const unsigned short* Wt = (which == 0) ? Wq : (which == 1) ? Wk : Wv;
  const float* bias = (which == 0) ? bqp : (which == 1) ? bkp : bvp;

  f32x4 acc[4][4];
#pragma unroll
  for (int i = 0; i < 4; ++i)
#pragma unroll
    for (int j = 0; j < 4; ++j) acc[i][j] = Z4;

  float bv4[4];
#pragma unroll
  for (int nt = 0; nt < 4; ++nt) bv4[nt] = bias[nbase + wn * 64 + nt * 16 + li];

  const int lr8 = lane >> 3, lc = lane & 7;
  const int xc8 = (lc ^ lr8) * 8;
  const unsigned short* srcA = A + (size_t)(mbase + wave * 32 + lr8) * Dn + xc8;
  const unsigned short* srcB = Wt + (size_t)(nbase + wave * 32 + lr8) * Dn + xc8;

  for (int kb = 0; kb < Dn; kb += 64) {
    __syncthreads();
#pragma unroll
    for (int i = 0; i < 4; ++i) {
      gll16(srcA + kb + (size_t)i * (8 * Dn), &Al[(wave * 32 + i * 8) * 64]);
      gll16(srcB + kb + (size_t)i * (8 * Dn), &Bl[(wave * 32 + i * 8) * 64]);
    }
    __syncthreads();
#pragma unroll
    for (int kc = 0; kc < 2; ++kc) {
      bf16x8 af[4], bfr[4];
#pragma unroll
      for (int mt = 0; mt < 4; ++mt) af[mt] = FR(Al, wm * 64 + mt * 16 + li, kc * 4 + g);
#pragma unroll
      for (int nt = 0; nt < 4; ++nt) bfr[nt] = FR(Bl, wn * 64 + nt * 16 + li, kc * 4 + g);
#pragma unroll
      for (int mt = 0; mt < 4; ++mt)
#pragma unroll
        for (int nt = 0; nt < 4; ++nt)
          acc[mt][nt] = MFMA(af[mt], bfr[nt], acc[mt][nt]);
    }
  }

  if (which < 2) {
    unsigned short* Ob = (which == 0) ? Qb : Kb;
    unsigned short* Or = (which == 0) ? Qr : Kr;
    const float presc = (which == 0) ? PRESC : 1.f;
#pragma unroll
    for (int mt = 0; mt < 4; ++mt) {
#pragma unroll
      for (int nt = 0; nt < 4; ++nt) {
        const int n = nbase + wn * 64 + nt * 16 + li;
        const int h = n >> 6, hd = n & 63;
        const int ti = hd >> 1;
        const float sgn = (hd & 1) ? 1.f : -1.f;
#pragma unroll
        for (int r = 0; r < 4; ++r) {
          const int m = mbase + wm * 64 + mt * 16 + 4 * g + r;
          const int b = m >> 11, s = m & (Sn - 1);
          const float v = (acc[mt][nt][r] + bv4[nt]) * presc;
          const size_t oi = (((size_t)(b * Hn + h)) * Sn + s) * HDn + hd;
          Ob[oi] = f2bf(v);
          const float p = __shfl_xor(v, 1);
          const float2 cs = trig[(s << 5) + ti];
          Or[oi] = f2bf(fmaf(sgn * p, cs.y, v * cs.x));
        }
      }
    }
  } else {
#pragma unroll
    for (int mt = 0; mt < 4; ++mt) {
#pragma unroll
      for (int nt = 0; nt < 4; ++nt) {
        const int n = nbase + wn * 64 + nt * 16 + li;
        const int h = n >> 6, hd = n & 63;
        const int m0 = mbase + wm * 64 + mt * 16 + 4 * g;
        const int b = m0 >> 11, s0 = m0 & (Sn - 1);
        u16x4 pk;
#pragma unroll
        for (int r = 0; r < 4; ++r) pk[r] = f2bf(acc[mt][nt][r] + bv4[nt]);
        *(u16x4*)&Vt[(((size_t)(b * Hn + h)) * HDn + hd) * Sn + s0] = pk;
      }
    }
  }
}

// ---------------------------------------------------------------------------
// 4. Output GEMM 64x128 tile (gll-staged): A bf16 [4096][1024], out f32 + bias
// ---------------------------------------------------------------------------
__global__ __launch_bounds__(256) void k_gemm_out(const unsigned short* __restrict__ A,
                                                  const unsigned short* __restrict__ Wt,
                                                  const float* __restrict__ bias,
                                                  float* __restrict__ out) {
  __shared__ unsigned short Al[64 * 64];
  __shared__ unsigned short Bl[128 * 64];
  const int tid = threadIdx.x;
  const int wave = tid >> 6, lane = tid & 63, g = lane >> 4, li = lane & 15;
  const int mbase = blockIdx.x * 64, nbase = blockIdx.y * 128;
  const int wm = wave >> 1, wn = wave & 1;

  f32x4 acc[2][4];
#pragma unroll
  for (int i = 0; i < 2; ++i)
#pragma unroll
    for (int j = 0; j < 4; ++j) acc[i][j] = Z4;

  float bv4[4];
#pragma unroll
  for (int nt = 0; nt < 4; ++nt) bv4[nt] = bias[nbase + wn * 64 + nt * 16 + li];

  const int lr8 = lane >> 3, lc = lane & 7;
  const int xc8 = (lc ^ lr8) * 8;
  const unsigned short* srcA = A + (size_t)(mbase + wave * 16 + lr8) * Dn + xc8;
  const unsigned short* srcB = Wt + (size_t)(nbase + wave * 32 + lr8) * Dn + xc8;

  for (int kb = 0; kb < Dn; kb += 64) {
    __syncthreads();
#pragma unroll
    for (int i = 0; i < 2; ++i)
      gll16(srcA + kb + (size_t)i * (8 * Dn), &Al[(wave * 16 + i * 8) * 64]);
#pragma unroll
    for (int i = 0; i < 4; ++i)
      gll16(srcB + kb + (size_t)i * (8 * Dn), &Bl[(wave * 32 + i * 8) * 64]);
    __syncthreads();
#pragma unroll
    for (int kc = 0; kc < 2; ++kc) {
      bf16x8 af[2], bfr[4];
#pragma unroll
      for (int mt = 0; mt < 2; ++mt) af[mt] = FR(Al, wm * 32 + mt * 16 + li, kc * 4 + g);
#pragma unroll
      for (int nt = 0; nt < 4; ++nt) bfr[nt] = FR(Bl, wn * 64 + nt * 16 + li, kc * 4 + g);
#pragma unroll
      for (int mt = 0; mt < 2; ++mt)
#pragma unroll
        for (int nt = 0; nt < 4; ++nt)
          acc[mt][nt] = MFMA(af[mt], bfr[nt], acc[mt][nt]);
    }
  }

#pragma unroll
  for (int mt = 0; mt < 2; ++mt)
#pragma unroll
    for (int nt = 0; nt < 4; ++nt) {
      const int n = nbase + wn * 64 + nt * 16 + li;
#pragma unroll
      for (int r = 0; r < 4; ++r) {
        const int m = mbase + wm * 32 + mt * 16 + 4 * g + r;
        out[(size_t)m * Dn + n] = acc[mt][nt][r] + bv4[nt];
      }
    }
}

// ---------------------------------------------------------------------------
// 5. Attention. grid 1024 blocks (balanced qt map), 4 waves x 16 q-rows each.
//    Swapped QK^T, exp2 algebra, NO max tracking (A <= ~0.25 << overflow for
//    this data; same-result guard as round 4 where rescale never fired).
//    LDS 40 KB -> 4 blocks/CU, 4 waves/SIMD.
// ---------------------------------------------------------------------------
__global__ __launch_bounds__(256, 4) void k_attn(
    const unsigned short* __restrict__ Qr, const unsigned short* __restrict__ Kr,
    const unsigned short* __restrict__ Qb, const unsigned short* __restrict__ Kb,
    const unsigned short* __restrict__ Vt, unsigned short* __restrict__ Zb) {
  __shared__ unsigned short KT[2][8192];  // 32 KB: passA = 128x64 Kb; passB = [Kr 64x64 | Vt 64x64]
  __shared__ unsigned short Pl[4][1024];  // 8 KB per-wave P [q][k] swizzled

  const int tid = threadIdx.x;
  const int wave = tid >> 6, lane = tid & 63, g = lane >> 4, li = lane & 15;
  // balanced qt assignment: any 4 consecutive bids have qt summing to 62
  const int bid = blockIdx.x;
  const int i4 = bid & 3, j = bid >> 2;
  const int bh = j & 31, grp = j >> 5;  // grp 0..7
  const int qt = (i4 == 0) ? grp : (i4 == 1) ? 15 - grp : (i4 == 2) ? 16 + grp : 31 - grp;
  const int qw = qt * 64 + wave * 16;
  const size_t kvbase = (size_t)bh * (Sn * HDn);

  // Q fragments (prescaled by PRESC at projection)
  bf16x8 qrf[2], qbf[2];
#pragma unroll
  for (int kc = 0; kc < 2; ++kc) {
    const size_t a = kvbase + (size_t)(qw + li) * HDn + kc * 32 + g * 8;
    qrf[kc] = *(const bf16x8*)(Qr + a);
    qbf[kc] = *(const bf16x8*)(Qb + a);
  }

  const int lr8 = lane >> 3, lc = lane & 7;
  const int xc8 = (lc ^ lr8) * 8;  // source-side swizzle

  // pass A: whole block stages one 128x64 Kb tile; wave covers rows wave*32..+31
  const unsigned short* srcPA = Kb + kvbase + (size_t)(wave * 32 + lr8) * HDn + xc8;
  // pass B: tw = tensor (0=Kr rows k, 1=Vt rows hd), rbB = row base
  const int tw = wave >> 1, rbB = (wave & 1) * 32;
  const unsigned short* srcKrB = Kr + kvbase + (size_t)(rbB + lr8) * HDn + xc8;
  const unsigned short* srcVtB = Vt + kvbase + (size_t)(rbB + lr8) * Sn + xc8;
  const size_t strIB = tw ? (size_t)(8 * Sn) : (size_t)(8 * HDn);
  unsigned short* myP = &Pl[wave][0];

  // diag masks: k-offset 4g+r causal-valid vs q-offset li (tile-invariant)
  bool dm[4];
#pragma unroll
  for (int r = 0; r < 4; ++r) dm[r] = (4 * g + r) <= li;

#define STAGE_PA(kb_, buf_)                                 \
  do {                                                      \
    unsigned short* d_ = &KT[buf_][(wave * 32) * 64];       \
    const unsigned short* s_ = srcPA + (size_t)(kb_)*HDn;   \
    gll16(s_, d_);                                          \
    gll16(s_ + 8 * HDn, d_ + 8 * 64);                       \
    gll16(s_ + 16 * HDn, d_ + 16 * 64);                     \
    gll16(s_ + 24 * HDn, d_ + 24 * 64);                     \
  } while (0)

#define STAGE_B(kb_, buf_)                                                    \
  do {                                                                        \
    unsigned short* d_ = &KT[buf_][tw * 4096 + rbB * 64];                     \
    const unsigned short* s_ =                                                \
        tw ? (srcVtB + (size_t)(kb_)) : (srcKrB + (size_t)(kb_)*HDn);         \
    gll16(s_, d_);                                                            \
    gll16(s_ + strIB, d_ + 8 * 64);                                           \
    gll16(s_ + 2 * strIB, d_ + 16 * 64);                                      \
    gll16(s_ + 3 * strIB, d_ + 24 * 64);                                      \
  } while (0)

  // ------------------- PASS A: den = sum over ALL k of 2^(s') -------------------
  float d4[4] = {0.f, 0.f, 0.f, 0.f};
  STAGE_PA(0, 0);
  __syncthreads();
  for (int t = 0; t < Sn / 128; ++t) {
    if (t + 1 < Sn / 128) STAGE_PA((t + 1) * 128, (t + 1) & 1);
    const unsigned short* TK = &KT[t & 1][0];
#pragma unroll
    for (int nt = 0; nt < 8; ++nt) {
      const int krow = nt * 16 + li;
      const bf16x8 kf0 = FR(TK, krow, g), kf1 = FR(TK, krow, 4 + g);
      f32x4 s = Z4;
      s = MFMA(kf0, qbf[0], s);
      s = MFMA(kf1, qbf[1], s);
#pragma unroll
      for (int r = 0; r < 4; ++r) d4[r] += EXP2(s[r]);
    }
    __syncthreads();
  }
  float den = (d4[0] + d4[1]) + (d4[2] + d4[3]);
  den += __shfl_xor(den, 16);
  den += __shfl_xor(den, 32);
  const float Lc = LOG2(den) - C2;  // lane's q = qw+li; A = 2^(s' - Lc)
  const f32x4 mLc = {-Lc, -Lc, -Lc, -Lc};

  // ------------------- PASS B: w = 2^A (no max; A bounded), Z = P.V -------------
  f32x4 accz[4];
#pragma unroll
  for (int i = 0; i < 4; ++i) accz[i] = Z4;
  float ws[4] = {0.f, 0.f, 0.f, 0.f};
  const int NTB = qt + 1;

  STAGE_B(0, 0);
  __syncthreads();
  for (int t = 0; t < NTB; ++t) {
    if (t + 1 < NTB) STAGE_B((t + 1) * 64, (t + 1) & 1);
    const unsigned short* T0 = &KT[t & 1][0];         // Kr [k][hd]
    const unsigned short* TV = &KT[t & 1][0] + 4096;  // Vt [hd][k]
    const bool last = (t == qt);
#pragma unroll
    for (int nt = 0; nt < 4; ++nt) {
      float w[4];
      if (!last || nt <= wave) {
        const int krow = nt * 16 + li;
        const bf16x8 kf0 = FR(T0, krow, g), kf1 = FR(T0, krow, 4 + g);
        f32x4 s = mLc;
        s = MFMA(kf0, qrf[0], s);
        s = MFMA(kf1, qrf[1], s);
        if (last && nt == wave) {  // diagonal subtile
#pragma unroll
          for (int r = 0; r < 4; ++r) {
            const float e = EXP2(EXP2(s[r]));
            w[r] = dm[r] ? e : 0.f;
            ws[r] += w[r];
          }
        } else {
#pragma unroll
          for (int r = 0; r < 4; ++r) {
            w[r] = EXP2(EXP2(s[r]));
            ws[r] += w[r];
          }
        }
      } else {
        w[0] = w[1] = w[2] = w[3] = 0.f;
      }
      const int adr = li * 64 + (((nt * 2 + (g >> 1)) ^ (li & 7)) * 8) + (g & 1) * 4;
      *(uint2*)&myP[adr] = (uint2){cvtpk(w[0], w[1]), cvtpk(w[2], w[3])};
    }
    // PV: accz[n2] = Z[q = qw+4g+r][hd = n2*16+li]
#pragma unroll
    for (int kc = 0; kc < 2; ++kc) {
      const bf16x8 pa = FR(myP, li, kc * 4 + g);
#pragma unroll
      for (int n2 = 0; n2 < 4; ++n2) {
        const bf16x8 vb = FR(TV, n2 * 16 + li, kc * 4 + g);
        accz[n2] = MFMA(pa, vb, accz[n2]);
      }
    }
    __syncthreads();
  }

  // normalize + write bf16 [b*S+q][H*HD]
  float wsum = (ws[0] + ws[1]) + (ws[2] + ws[3]);
  wsum += __shfl_xor(wsum, 16);
  wsum += __shfl_xor(wsum, 32);  // lane holds wsum for q = qw+li
  float rw[4];
#pragma unroll
  for (int r = 0; r < 4; ++r) rw[r] = 1.f / __shfl(wsum, 4 * g + r);
  const int b = bh >> 4, h = bh & 15;
#pragma unroll
  for (int n2 = 0; n2 < 4; ++n2) {
#pragma unroll
    for (int r = 0; r < 4; ++r) {
      const int hd = n2 * 16 + li;
      const int q = qw + 4 * g + r;
      Zb[((size_t)(b * Sn + q)) * Dn + h * HDn + hd] = f2bf(accz[n2][r] * rw[r]);
    }
  }
#undef STAGE_PA
#undef STAGE_B
}

// ---------------------------------------------------------------------------
extern "C" void kernel_launch(void* const* d_in, const int* in_sizes, int n_in,
                              void* d_out, int out_size, void* d_ws, size_t ws_size,
                              hipStream_t stream) {
  const float* query = (const float*)d_in[0];
  const float* key   = (const float*)d_in[1];
  const float* value = (const float*)d_in[2];
  const float* Wq = (const float*)d_in[4];
  const float* bq = (const float*)d_in[5];
  const float* Wk = (const float*)d_in[6];
  const float* bk = (const float*)d_in[7];
  const float* Wv = (const float*)d_in[8];
  const float* bv = (const float*)d_in[9];
  const float* Wo = (const float*)d_in[10];
  const float* bo = (const float*)d_in[11];

  char* ws = (char*)d_ws;
  const size_t MB = 1ull << 20;
  unsigned short* Wqt = (unsigned short*)(ws + 0 * MB);
  unsigned short* Wkt = (unsigned short*)(ws + 2 * MB);
  unsigned short* Wvt = (unsigned short*)(ws + 4 * MB);
  unsigned short* Wot = (unsigned short*)(ws + 6 * MB);
  float2* trig        = (float2*)(ws + 8 * MB);           // 512 KB
  unsigned short* Qa  = (unsigned short*)(ws + 9 * MB);   // bf16 activations
  unsigned short* Ka  = (unsigned short*)(ws + 17 * MB);
  unsigned short* Va  = (unsigned short*)(ws + 25 * MB);
  unsigned short* Qb  = (unsigned short*)(ws + 33 * MB);  // [b,h,s,hd] bf16 (Q prescaled)
  unsigned short* Kb  = (unsigned short*)(ws + 41 * MB);
  unsigned short* Qr  = (unsigned short*)(ws + 49 * MB);
  unsigned short* Kr  = (unsigned short*)(ws + 57 * MB);
  unsigned short* Vt  = (unsigned short*)(ws + 65 * MB);  // [b,h,hd,s] bf16
  unsigned short* Zb  = (unsigned short*)(ws + 73 * MB);  // [m][1024] bf16

  k_trig<<<256, 256, 0, stream>>>(trig);
  k_wtrans<<<dim3(16, 16, 4), 256, 0, stream>>>(Wq, Wk, Wv, Wo, Wqt, Wkt, Wvt, Wot);
  k_cvt<<<dim3(2048, 3), 256, 0, stream>>>(query, key, value, Qa, Ka, Va);
  k_gemm_proj<<<dim3(32, 8, 3), 256, 0, stream>>>(Qa, Ka, Va, Wqt, Wkt, Wvt,
                                                  bq, bk, bv, trig, Qb, Kb, Qr, Kr, Vt);
  k_attn<<<1024, 256, 0, stream>>>(Qr, Kr, Qb, Kb, Vt, Zb);
  k_gemm_out<<<dim3(64, 8), 256, 0, stream>>>(Zb, Wot, bo, (float*)d_out);
}